// Round 1
// baseline (1730.963 us; speedup 1.0000x reference)
//
#include <hip/hip_runtime.h>
#include <hip/hip_bf16.h>

// ---------------------------------------------------------------------------
// GCN 2-layer forward:
//   x1 = relu( Ahat @ (X W1) + b1 ),  out = Ahat @ (x1 W2) + b2
//   return log_softmax(out), softmax(out)
// Ahat = D^{-1/2}(A+I)D^{-1/2}; deg = in-degree(dst)+1.
// Strategy: counting-sort edges into CSR-by-dst (atomic-free aggregation),
// precompute per-edge norm, tiled f32 GEMM1, wave-per-node agg kernels.
// ---------------------------------------------------------------------------

#define F_IN 512
#define HID  256
#define NCLS 40

// ---------------- edge dtype detect (int64 vs int32) ----------------
__global__ void detect64_kernel(const int* __restrict__ ei, int* __restrict__ flag) {
    __shared__ int any_nz;
    if (threadIdx.x == 0) any_nz = 0;
    __syncthreads();
    int nz = 0;
    for (int i = threadIdx.x; i < 4096; i += 256) {
        nz |= (ei[2 * i + 1] != 0);
    }
    if (nz) atomicOr(&any_nz, 1);
    __syncthreads();
    if (threadIdx.x == 0) *flag = any_nz ? 0 : 1;  // 1 => int64 layout
}

__device__ inline int edge_src(const int* ei, long long E, int e, int is64) {
    return is64 ? ei[2LL * e] : ei[e];
}
__device__ inline int edge_dst(const int* ei, long long E, int e, int is64) {
    return is64 ? ei[2LL * (E + e)] : ei[(int)E + e];
}

// ---------------- degree count ----------------
__global__ void count_kernel(const int* __restrict__ ei, int E,
                             const int* __restrict__ flag, int* __restrict__ cnt) {
    int e = blockIdx.x * 256 + threadIdx.x;
    if (e >= E) return;
    int is64 = *flag;
    int d = edge_dst(ei, E, e, is64);
    atomicAdd(&cnt[d], 1);
}

// ---------------- scan (3-phase) ----------------
__global__ __launch_bounds__(256) void scan_block_sums(const int* __restrict__ cnt,
                                                       int* __restrict__ blockSums, int Nn) {
    __shared__ int sdata[256];
    int b = blockIdx.x, t = threadIdx.x;
    int sum = 0;
    int i0 = b * 1024 + t * 4;
    for (int i = 0; i < 4; ++i) {
        int idx = i0 + i;
        if (idx < Nn) sum += cnt[idx];
    }
    sdata[t] = sum;
    __syncthreads();
    for (int s = 128; s > 0; s >>= 1) {
        if (t < s) sdata[t] += sdata[t + s];
        __syncthreads();
    }
    if (t == 0) blockSums[b] = sdata[0];
}

__global__ void scan_sums_kernel(int* __restrict__ blockSums, int nB,
                                 int* __restrict__ rowStart, int Nn) {
    if (threadIdx.x == 0 && blockIdx.x == 0) {
        int run = 0;
        for (int i = 0; i < nB; ++i) { int v = blockSums[i]; blockSums[i] = run; run += v; }
        rowStart[Nn] = run;  // == E
    }
}

__global__ __launch_bounds__(256) void scan_final(const int* __restrict__ cnt,
                                                  const int* __restrict__ blockSumsEx,
                                                  int* __restrict__ rowStart,
                                                  int* __restrict__ rowPos, int Nn) {
    __shared__ int sdata[256];
    int b = blockIdx.x, t = threadIdx.x;
    int base = blockSumsEx[b];
    int vals[4];
    int sum = 0;
    int i0 = b * 1024 + t * 4;
    for (int i = 0; i < 4; ++i) {
        int idx = i0 + i;
        vals[i] = (idx < Nn) ? cnt[idx] : 0;
        sum += vals[i];
    }
    sdata[t] = sum;
    __syncthreads();
    // Hillis-Steele inclusive scan over 256 thread sums
    for (int off = 1; off < 256; off <<= 1) {
        int y = (t >= off) ? sdata[t - off] : 0;
        __syncthreads();
        sdata[t] += y;
        __syncthreads();
    }
    int run = base + (sdata[t] - sum);  // exclusive
    for (int i = 0; i < 4; ++i) {
        int idx = i0 + i;
        if (idx < Nn) { rowStart[idx] = run; rowPos[idx] = run; }
        run += vals[i];
    }
}

// ---------------- dinv ----------------
__global__ void dinv_kernel(const int* __restrict__ cnt, float* __restrict__ dinv, int Nn) {
    int i = blockIdx.x * 256 + threadIdx.x;
    if (i < Nn) dinv[i] = rsqrtf((float)cnt[i] + 1.0f);
}

// ---------------- CSR fill (+norm precompute) ----------------
__global__ void fill_kernel(const int* __restrict__ ei, int E, const int* __restrict__ flag,
                            const float* __restrict__ dinv, int* __restrict__ rowPos,
                            int* __restrict__ csrSrc, float* __restrict__ csrNorm) {
    int e = blockIdx.x * 256 + threadIdx.x;
    if (e >= E) return;
    int is64 = *flag;
    int s = edge_src(ei, E, e, is64);
    int d = edge_dst(ei, E, e, is64);
    int p = atomicAdd(&rowPos[d], 1);
    csrSrc[p] = s;
    csrNorm[p] = dinv[s] * dinv[d];
}

// ---------------- GEMM1: h1[M,256] = X[M,512] @ W1[512,256], f32 tiled ------
#define TM 128
#define TN 128
#define TK 16
__global__ __launch_bounds__(256) void gemm1_kernel(const float* __restrict__ A,
                                                    const float* __restrict__ B,
                                                    float* __restrict__ C, int M) {
    __shared__ float As[TK][TM];
    __shared__ float Bs[TK][TN];
    const int K = F_IN, N = HID;
    int tid = threadIdx.x;
    int bm = blockIdx.x * TM;
    int bn = blockIdx.y * TN;
    int tx = tid % 16, ty = tid / 16;
    int m0 = ty * 8, n0 = tx * 8;
    float acc[8][8] = {};
    for (int k0 = 0; k0 < K; k0 += TK) {
        // A tile 128x16 -> As[k][m] (transposed store)
#pragma unroll
        for (int i = 0; i < 2; ++i) {
            int idx = (tid + i * 256) * 4;   // 0..2044, multiple of 4
            int m = idx / TK;
            int k = idx % TK;
            float4 v = make_float4(0.f, 0.f, 0.f, 0.f);
            int gm = bm + m;
            if (gm < M) v = *(const float4*)&A[(size_t)gm * K + k0 + k];
            As[k + 0][m] = v.x; As[k + 1][m] = v.y; As[k + 2][m] = v.z; As[k + 3][m] = v.w;
        }
        // B tile 16x128 -> Bs[k][n]
#pragma unroll
        for (int i = 0; i < 2; ++i) {
            int idx = (tid + i * 256) * 4;
            int k = idx / TN;
            int n = idx % TN;
            *(float4*)&Bs[k][n] = *(const float4*)&B[(size_t)(k0 + k) * N + bn + n];
        }
        __syncthreads();
#pragma unroll
        for (int k = 0; k < TK; ++k) {
            float a[8], b[8];
#pragma unroll
            for (int i = 0; i < 8; ++i) a[i] = As[k][m0 + i];
#pragma unroll
            for (int j = 0; j < 8; ++j) b[j] = Bs[k][n0 + j];
#pragma unroll
            for (int i = 0; i < 8; ++i)
#pragma unroll
                for (int j = 0; j < 8; ++j) acc[i][j] += a[i] * b[j];
        }
        __syncthreads();
    }
#pragma unroll
    for (int i = 0; i < 8; ++i) {
        int gm = bm + m0 + i;
        if (gm < M) {
#pragma unroll
            for (int j = 0; j < 8; j += 4)
                *(float4*)&C[(size_t)gm * N + bn + n0 + j] = *(float4*)&acc[i][j];
        }
    }
}

// ---------------- Agg1 + bias + relu: wave per node, 256 cols --------------
__global__ __launch_bounds__(256) void agg1_kernel(const float* __restrict__ h1,
                                                   const int* __restrict__ rowStart,
                                                   const int* __restrict__ csrSrc,
                                                   const float* __restrict__ csrNorm,
                                                   const float* __restrict__ dinv,
                                                   const float* __restrict__ b1,
                                                   float* __restrict__ x1, int Nn) {
    int n = blockIdx.x * 4 + (threadIdx.x >> 6);
    int lane = threadIdx.x & 63;
    if (n >= Nn) return;
    float4 acc = make_float4(0.f, 0.f, 0.f, 0.f);
    int s0 = rowStart[n], s1 = rowStart[n + 1];
    for (int e = s0; e < s1; ++e) {
        int s = csrSrc[e];
        float nrm = csrNorm[e];
        float4 v = *(const float4*)(h1 + (size_t)s * HID + lane * 4);
        acc.x += nrm * v.x; acc.y += nrm * v.y; acc.z += nrm * v.z; acc.w += nrm * v.w;
    }
    float di = dinv[n];
    float self = di * di;
    float4 hv = *(const float4*)(h1 + (size_t)n * HID + lane * 4);
    float4 bv = *(const float4*)(b1 + lane * 4);
    acc.x = fmaxf(acc.x + self * hv.x + bv.x, 0.f);
    acc.y = fmaxf(acc.y + self * hv.y + bv.y, 0.f);
    acc.z = fmaxf(acc.z + self * hv.z + bv.z, 0.f);
    acc.w = fmaxf(acc.w + self * hv.w + bv.w, 0.f);
    *(float4*)(x1 + (size_t)n * HID + lane * 4) = acc;
}

// ---------------- GEMM2: h2[M,40] = x1[M,256] @ W2[256,40], wave per node --
__global__ __launch_bounds__(256) void gemm2_kernel(const float* __restrict__ x1,
                                                    const float* __restrict__ W2,
                                                    float* __restrict__ h2, int Nn) {
    int n = blockIdx.x * 4 + (threadIdx.x >> 6);
    int lane = threadIdx.x & 63;
    if (n >= Nn) return;
    const float* xr = x1 + (size_t)n * HID;
    float acc = 0.f;
    for (int k = 0; k < HID; k += 4) {
        float4 xv = *(const float4*)(xr + k);
        if (lane < NCLS) {
            acc += xv.x * W2[(k + 0) * NCLS + lane];
            acc += xv.y * W2[(k + 1) * NCLS + lane];
            acc += xv.z * W2[(k + 2) * NCLS + lane];
            acc += xv.w * W2[(k + 3) * NCLS + lane];
        }
    }
    if (lane < NCLS) h2[(size_t)n * NCLS + lane] = acc;
}

// ---------------- Agg2 + bias + softmax/log_softmax ------------------------
__global__ __launch_bounds__(256) void agg2_kernel(const float* __restrict__ h2,
                                                   const int* __restrict__ rowStart,
                                                   const int* __restrict__ csrSrc,
                                                   const float* __restrict__ csrNorm,
                                                   const float* __restrict__ dinv,
                                                   const float* __restrict__ b2,
                                                   float* __restrict__ out, int Nn) {
    int n = blockIdx.x * 4 + (threadIdx.x >> 6);
    int lane = threadIdx.x & 63;
    if (n >= Nn) return;
    bool act = lane < NCLS;
    float acc = 0.f;
    int s0 = rowStart[n], s1 = rowStart[n + 1];
    for (int e = s0; e < s1; ++e) {
        int s = csrSrc[e];
        float nrm = csrNorm[e];
        if (act) acc += nrm * h2[(size_t)s * NCLS + lane];
    }
    float di = dinv[n];
    if (act) acc += di * di * h2[(size_t)n * NCLS + lane] + b2[lane];
    float v = act ? acc : -3.4e38f;
#pragma unroll
    for (int off = 32; off > 0; off >>= 1) v = fmaxf(v, __shfl_xor(v, off));
    float ex = act ? expf(acc - v) : 0.f;
    float ssum = ex;
#pragma unroll
    for (int off = 32; off > 0; off >>= 1) ssum += __shfl_xor(ssum, off);
    if (act) {
        float ls = acc - v - logf(ssum);
        out[(size_t)n * NCLS + lane] = ls;                          // log_softmax
        out[(size_t)Nn * NCLS + (size_t)n * NCLS + lane] = ex / ssum;  // softmax
    }
}

// ---------------------------------------------------------------------------
extern "C" void kernel_launch(void* const* d_in, const int* in_sizes, int n_in,
                              void* d_out, int out_size, void* d_ws, size_t ws_size,
                              hipStream_t stream) {
    const float* features = (const float*)d_in[0];
    const float* W1 = (const float*)d_in[1];
    const float* b1 = (const float*)d_in[2];
    const float* W2 = (const float*)d_in[3];
    const float* b2 = (const float*)d_in[4];
    const int* edge_index = (const int*)d_in[5];

    const int N = in_sizes[0] / F_IN;       // 100000
    const int E = in_sizes[5] / 2;          // 1600000
    float* out = (float*)d_out;

    // workspace carve-up
    auto align256 = [](size_t x) { return (x + 255) & ~(size_t)255; };
    char* w = (char*)d_ws;
    int* cnt       = (int*)w;  w += align256((size_t)N * 4);
    int* rowStart  = (int*)w;  w += align256((size_t)(N + 1) * 4);
    int* rowPos    = (int*)w;  w += align256((size_t)N * 4);
    int* blockSums = (int*)w;  w += align256(1024 * 4);
    int* flag64    = (int*)w;  w += 256;
    int* csrSrc    = (int*)w;  w += align256((size_t)E * 4);
    float* csrNorm = (float*)w; w += align256((size_t)E * 4);
    float* dinv    = (float*)w; w += align256((size_t)N * 4);
    float* h1      = (float*)w; w += align256((size_t)N * HID * 4);
    float* x1      = (float*)w; w += align256((size_t)N * HID * 4);
    float* h2      = (float*)w; w += align256((size_t)N * NCLS * 4);
    (void)ws_size;

    const int nB = (N + 1023) / 1024;
    const int eBlocks = (E + 255) / 256;
    const int nBlocks = (N + 255) / 256;
    const int waveBlocks = (N + 3) / 4;   // 4 waves (nodes) per 256-thread block

    hipMemsetAsync(cnt, 0, (size_t)N * 4, stream);
    detect64_kernel<<<1, 256, 0, stream>>>(edge_index, flag64);
    count_kernel<<<eBlocks, 256, 0, stream>>>(edge_index, E, flag64, cnt);
    scan_block_sums<<<nB, 256, 0, stream>>>(cnt, blockSums, N);
    scan_sums_kernel<<<1, 64, 0, stream>>>(blockSums, nB, rowStart, N);
    dinv_kernel<<<nBlocks, 256, 0, stream>>>(cnt, dinv, N);
    scan_final<<<nB, 256, 0, stream>>>(cnt, blockSums, rowStart, rowPos, N);
    fill_kernel<<<eBlocks, 256, 0, stream>>>(edge_index, E, flag64, dinv, rowPos,
                                             csrSrc, csrNorm);

    dim3 g1((N + TM - 1) / TM, HID / TN);
    gemm1_kernel<<<g1, 256, 0, stream>>>(features, W1, h1, N);
    agg1_kernel<<<waveBlocks, 256, 0, stream>>>(h1, rowStart, csrSrc, csrNorm, dinv,
                                                b1, x1, N);
    gemm2_kernel<<<waveBlocks, 256, 0, stream>>>(x1, W2, h2, N);
    agg2_kernel<<<waveBlocks, 256, 0, stream>>>(h2, rowStart, csrSrc, csrNorm, dinv,
                                                b2, out, N);
}

// Round 2
// 1237.654 us; speedup vs baseline: 1.3986x; 1.3986x over previous
//
#include <hip/hip_runtime.h>
#include <hip/hip_bf16.h>

// ---------------------------------------------------------------------------
// GCN 2-layer forward (f32 in/out), MFMA bf16 GEMM1:
//   x1 = relu( Ahat @ (X W1) + b1 ),  out = Ahat @ (x1 W2) + b2
//   return log_softmax(out), softmax(out)
// Round 2: GEMM1 via mfma_f32_16x16x32_bf16 (X, W1 pre-cast to bf16; W1
// transposed to n-major so A and B^T fragments share one LDS layout).
// h1 kept bf16 -> halves agg1 gather bytes. CSR build unchanged.
// ---------------------------------------------------------------------------

#define F_IN 512
#define HID  256
#define NCLS 40

typedef __attribute__((ext_vector_type(8))) short bf16x8;
typedef __attribute__((ext_vector_type(4))) float floatx4;

__device__ inline unsigned short f2bf(float v) {
    unsigned u = __float_as_uint(v);
    u += 0x7fffu + ((u >> 16) & 1u);   // round-to-nearest-even
    return (unsigned short)(u >> 16);
}
__device__ inline float bf2f(unsigned short u) {
    return __uint_as_float(((unsigned)u) << 16);
}

// ---------------- edge dtype detect (int64 vs int32) ----------------
__global__ void detect64_kernel(const int* __restrict__ ei, int* __restrict__ flag) {
    __shared__ int any_nz;
    if (threadIdx.x == 0) any_nz = 0;
    __syncthreads();
    int nz = 0;
    for (int i = threadIdx.x; i < 4096; i += 256) {
        nz |= (ei[2 * i + 1] != 0);
    }
    if (nz) atomicOr(&any_nz, 1);
    __syncthreads();
    if (threadIdx.x == 0) *flag = any_nz ? 0 : 1;  // 1 => int64 layout
}

__device__ inline int edge_src(const int* ei, long long E, int e, int is64) {
    return is64 ? ei[2LL * e] : ei[e];
}
__device__ inline int edge_dst(const int* ei, long long E, int e, int is64) {
    return is64 ? ei[2LL * (E + e)] : ei[(int)E + e];
}

// ---------------- degree count ----------------
__global__ void count_kernel(const int* __restrict__ ei, int E,
                             const int* __restrict__ flag, int* __restrict__ cnt) {
    int e = blockIdx.x * 256 + threadIdx.x;
    if (e >= E) return;
    int is64 = *flag;
    int d = edge_dst(ei, E, e, is64);
    atomicAdd(&cnt[d], 1);
}

// ---------------- scan (3-phase) ----------------
__global__ __launch_bounds__(256) void scan_block_sums(const int* __restrict__ cnt,
                                                       int* __restrict__ blockSums, int Nn) {
    __shared__ int sdata[256];
    int b = blockIdx.x, t = threadIdx.x;
    int sum = 0;
    int i0 = b * 1024 + t * 4;
    for (int i = 0; i < 4; ++i) {
        int idx = i0 + i;
        if (idx < Nn) sum += cnt[idx];
    }
    sdata[t] = sum;
    __syncthreads();
    for (int s = 128; s > 0; s >>= 1) {
        if (t < s) sdata[t] += sdata[t + s];
        __syncthreads();
    }
    if (t == 0) blockSums[b] = sdata[0];
}

__global__ void scan_sums_kernel(int* __restrict__ blockSums, int nB,
                                 int* __restrict__ rowStart, int Nn) {
    if (threadIdx.x == 0 && blockIdx.x == 0) {
        int run = 0;
        for (int i = 0; i < nB; ++i) { int v = blockSums[i]; blockSums[i] = run; run += v; }
        rowStart[Nn] = run;  // == E
    }
}

__global__ __launch_bounds__(256) void scan_final(const int* __restrict__ cnt,
                                                  const int* __restrict__ blockSumsEx,
                                                  int* __restrict__ rowStart,
                                                  int* __restrict__ rowPos, int Nn) {
    __shared__ int sdata[256];
    int b = blockIdx.x, t = threadIdx.x;
    int base = blockSumsEx[b];
    int vals[4];
    int sum = 0;
    int i0 = b * 1024 + t * 4;
    for (int i = 0; i < 4; ++i) {
        int idx = i0 + i;
        vals[i] = (idx < Nn) ? cnt[idx] : 0;
        sum += vals[i];
    }
    sdata[t] = sum;
    __syncthreads();
    for (int off = 1; off < 256; off <<= 1) {
        int y = (t >= off) ? sdata[t - off] : 0;
        __syncthreads();
        sdata[t] += y;
        __syncthreads();
    }
    int run = base + (sdata[t] - sum);  // exclusive
    for (int i = 0; i < 4; ++i) {
        int idx = i0 + i;
        if (idx < Nn) { rowStart[idx] = run; rowPos[idx] = run; }
        run += vals[i];
    }
}

// ---------------- dinv ----------------
__global__ void dinv_kernel(const int* __restrict__ cnt, float* __restrict__ dinv, int Nn) {
    int i = blockIdx.x * 256 + threadIdx.x;
    if (i < Nn) dinv[i] = rsqrtf((float)cnt[i] + 1.0f);
}

// ---------------- CSR fill (+norm precompute) ----------------
__global__ void fill_kernel(const int* __restrict__ ei, int E, const int* __restrict__ flag,
                            const float* __restrict__ dinv, int* __restrict__ rowPos,
                            int* __restrict__ csrSrc, float* __restrict__ csrNorm) {
    int e = blockIdx.x * 256 + threadIdx.x;
    if (e >= E) return;
    int is64 = *flag;
    int s = edge_src(ei, E, e, is64);
    int d = edge_dst(ei, E, e, is64);
    int p = atomicAdd(&rowPos[d], 1);
    csrSrc[p] = s;
    csrNorm[p] = dinv[s] * dinv[d];
}

// ---------------- bf16 conversions ----------------
// X [M,512] f32 -> Xb [Mpad,512] bf16 (pad rows zero)
__global__ __launch_bounds__(256) void convertX_kernel(const float* __restrict__ X,
                                                       unsigned short* __restrict__ Xb,
                                                       int realElems, int totElems) {
    int i = (blockIdx.x * 256 + threadIdx.x) * 4;
    if (i >= totElems) return;
    float4 v = make_float4(0.f, 0.f, 0.f, 0.f);
    if (i < realElems) v = *(const float4*)&X[i];
    ushort4 o;
    o.x = f2bf(v.x); o.y = f2bf(v.y); o.z = f2bf(v.z); o.w = f2bf(v.w);
    *(ushort4*)&Xb[i] = o;
}

// W1 [512,256] f32 -> W1t [256,512] bf16 (n-major)
__global__ __launch_bounds__(256) void convertW1t_kernel(const float* __restrict__ W1,
                                                         unsigned short* __restrict__ W1t) {
    int id = blockIdx.x * 256 + threadIdx.x;  // 512*256
    int k = id >> 8, n = id & 255;
    W1t[n * 512 + k] = f2bf(W1[id]);
}

// ---------------- GEMM1 MFMA: h1[Mpad,256](bf16) = Xb @ W1t^T ---------------
// Tile 128x128, BK=32, 4 waves: wave w -> (mblk,nblk) = ((w&1)*64,(w>>1)*64),
// each wave 4x4 grid of 16x16x32 MFMAs. LDS rows padded to 40 bf16 (80 B) so
// b128 fragment reads are <=2-way bank-aliased (free).
#define LDK 40
__global__ __launch_bounds__(256) void gemm1_mfma_kernel(const unsigned short* __restrict__ Xb,
                                                         const unsigned short* __restrict__ W1t,
                                                         unsigned short* __restrict__ h1) {
    __shared__ unsigned short As[128][LDK];
    __shared__ unsigned short Bs[128][LDK];
    const int tid = threadIdx.x;
    const int bm = blockIdx.x * 128;
    const int bn = blockIdx.y * 128;
    const int lane = tid & 63, w = tid >> 6;
    const int mblk = (w & 1) * 64, nblk = (w >> 1) * 64;
    const int lrow = lane & 15, lq = lane >> 4;

    floatx4 acc[4][4];
#pragma unroll
    for (int i = 0; i < 4; ++i)
#pragma unroll
        for (int j = 0; j < 4; ++j)
            acc[i][j] = (floatx4){0.f, 0.f, 0.f, 0.f};

    for (int k0 = 0; k0 < F_IN; k0 += 32) {
        // stage: 128x32 bf16 per tile; 512 chunks of 8 bf16; 2 chunks/thread
#pragma unroll
        for (int i = 0; i < 2; ++i) {
            int c = tid + i * 256;
            int row = c >> 2, kb = (c & 3) * 8;
            *(float4*)&As[row][kb] =
                *(const float4*)&Xb[(size_t)(bm + row) * F_IN + k0 + kb];
            *(float4*)&Bs[row][kb] =
                *(const float4*)&W1t[(size_t)(bn + row) * F_IN + k0 + kb];
        }
        __syncthreads();
        bf16x8 a[4], b[4];
#pragma unroll
        for (int mt = 0; mt < 4; ++mt)
            a[mt] = *(const bf16x8*)&As[mblk + mt * 16 + lrow][lq * 8];
#pragma unroll
        for (int nt = 0; nt < 4; ++nt)
            b[nt] = *(const bf16x8*)&Bs[nblk + nt * 16 + lrow][lq * 8];
#pragma unroll
        for (int mt = 0; mt < 4; ++mt)
#pragma unroll
            for (int nt = 0; nt < 4; ++nt)
                acc[mt][nt] = __builtin_amdgcn_mfma_f32_16x16x32_bf16(
                    a[mt], b[nt], acc[mt][nt], 0, 0, 0);
        __syncthreads();
    }
    // epilogue: C/D layout col=lane&15, row=(lane>>4)*4+r
#pragma unroll
    for (int mt = 0; mt < 4; ++mt) {
#pragma unroll
        for (int nt = 0; nt < 4; ++nt) {
            int gn = bn + nblk + nt * 16 + lrow;
            size_t gm0 = (size_t)(bm + mblk + mt * 16 + lq * 4);
#pragma unroll
            for (int r = 0; r < 4; ++r)
                h1[(gm0 + r) * HID + gn] = f2bf(acc[mt][nt][r]);
        }
    }
}

// ---------------- Agg1 + bias + relu: wave per node, h1 bf16 ---------------
__global__ __launch_bounds__(256) void agg1_kernel(const unsigned short* __restrict__ h1,
                                                   const int* __restrict__ rowStart,
                                                   const int* __restrict__ csrSrc,
                                                   const float* __restrict__ csrNorm,
                                                   const float* __restrict__ dinv,
                                                   const float* __restrict__ b1,
                                                   float* __restrict__ x1, int Nn) {
    int n = blockIdx.x * 4 + (threadIdx.x >> 6);
    int lane = threadIdx.x & 63;
    if (n >= Nn) return;
    float4 acc = make_float4(0.f, 0.f, 0.f, 0.f);
    int s0 = rowStart[n], s1 = rowStart[n + 1];
    if (s0 < s1) {
        int s = csrSrc[s0];
        float nrm = csrNorm[s0];
        for (int e = s0; e < s1; ++e) {
            int sn = 0; float nn = 0.f;
            if (e + 1 < s1) { sn = csrSrc[e + 1]; nn = csrNorm[e + 1]; }
            ushort4 v = *(const ushort4*)(h1 + (size_t)s * HID + lane * 4);
            acc.x += nrm * bf2f(v.x);
            acc.y += nrm * bf2f(v.y);
            acc.z += nrm * bf2f(v.z);
            acc.w += nrm * bf2f(v.w);
            s = sn; nrm = nn;
        }
    }
    float di = dinv[n];
    float self = di * di;
    ushort4 hv = *(const ushort4*)(h1 + (size_t)n * HID + lane * 4);
    float4 bv = *(const float4*)(b1 + lane * 4);
    acc.x = fmaxf(acc.x + self * bf2f(hv.x) + bv.x, 0.f);
    acc.y = fmaxf(acc.y + self * bf2f(hv.y) + bv.y, 0.f);
    acc.z = fmaxf(acc.z + self * bf2f(hv.z) + bv.z, 0.f);
    acc.w = fmaxf(acc.w + self * bf2f(hv.w) + bv.w, 0.f);
    *(float4*)(x1 + (size_t)n * HID + lane * 4) = acc;
}

// ---------------- GEMM2: h2[M,40] = x1[M,256] @ W2[256,40], wave per node --
__global__ __launch_bounds__(256) void gemm2_kernel(const float* __restrict__ x1,
                                                    const float* __restrict__ W2,
                                                    float* __restrict__ h2, int Nn) {
    int n = blockIdx.x * 4 + (threadIdx.x >> 6);
    int lane = threadIdx.x & 63;
    if (n >= Nn) return;
    const float* xr = x1 + (size_t)n * HID;
    float acc = 0.f;
    for (int k = 0; k < HID; k += 4) {
        float4 xv = *(const float4*)(xr + k);
        if (lane < NCLS) {
            acc += xv.x * W2[(k + 0) * NCLS + lane];
            acc += xv.y * W2[(k + 1) * NCLS + lane];
            acc += xv.z * W2[(k + 2) * NCLS + lane];
            acc += xv.w * W2[(k + 3) * NCLS + lane];
        }
    }
    if (lane < NCLS) h2[(size_t)n * NCLS + lane] = acc;
}

// ---------------- Agg2 + bias + softmax/log_softmax ------------------------
__global__ __launch_bounds__(256) void agg2_kernel(const float* __restrict__ h2,
                                                   const int* __restrict__ rowStart,
                                                   const int* __restrict__ csrSrc,
                                                   const float* __restrict__ csrNorm,
                                                   const float* __restrict__ dinv,
                                                   const float* __restrict__ b2,
                                                   float* __restrict__ out, int Nn) {
    int n = blockIdx.x * 4 + (threadIdx.x >> 6);
    int lane = threadIdx.x & 63;
    if (n >= Nn) return;
    bool act = lane < NCLS;
    float acc = 0.f;
    int s0 = rowStart[n], s1 = rowStart[n + 1];
    for (int e = s0; e < s1; ++e) {
        int s = csrSrc[e];
        float nrm = csrNorm[e];
        if (act) acc += nrm * h2[(size_t)s * NCLS + lane];
    }
    float di = dinv[n];
    if (act) acc += di * di * h2[(size_t)n * NCLS + lane] + b2[lane];
    float v = act ? acc : -3.4e38f;
#pragma unroll
    for (int off = 32; off > 0; off >>= 1) v = fmaxf(v, __shfl_xor(v, off));
    float ex = act ? expf(acc - v) : 0.f;
    float ssum = ex;
#pragma unroll
    for (int off = 32; off > 0; off >>= 1) ssum += __shfl_xor(ssum, off);
    if (act) {
        float ls = acc - v - logf(ssum);
        out[(size_t)n * NCLS + lane] = ls;                             // log_softmax
        out[(size_t)Nn * NCLS + (size_t)n * NCLS + lane] = ex / ssum;  // softmax
    }
}

// ---------------------------------------------------------------------------
extern "C" void kernel_launch(void* const* d_in, const int* in_sizes, int n_in,
                              void* d_out, int out_size, void* d_ws, size_t ws_size,
                              hipStream_t stream) {
    const float* features = (const float*)d_in[0];
    const float* W1 = (const float*)d_in[1];
    const float* b1 = (const float*)d_in[2];
    const float* W2 = (const float*)d_in[3];
    const float* b2 = (const float*)d_in[4];
    const int* edge_index = (const int*)d_in[5];

    const int N = in_sizes[0] / F_IN;        // 100000
    const int E = in_sizes[5] / 2;           // 1600000
    const int Mpad = (N + 127) & ~127;       // 100096
    float* out = (float*)d_out;

    auto align256 = [](size_t x) { return (x + 255) & ~(size_t)255; };
    char* w = (char*)d_ws;
    int* cnt        = (int*)w;  w += align256((size_t)N * 4);
    int* rowStart   = (int*)w;  w += align256((size_t)(N + 1) * 4);
    int* rowPos     = (int*)w;  w += align256((size_t)N * 4);
    int* blockSums  = (int*)w;  w += align256(1024 * 4);
    int* flag64     = (int*)w;  w += 256;
    int* csrSrc     = (int*)w;  w += align256((size_t)E * 4);
    float* csrNorm  = (float*)w; w += align256((size_t)E * 4);
    float* dinv     = (float*)w; w += align256((size_t)N * 4);
    unsigned short* Xb  = (unsigned short*)w; w += align256((size_t)Mpad * F_IN * 2);
    unsigned short* W1t = (unsigned short*)w; w += align256((size_t)HID * F_IN * 2);
    unsigned short* h1  = (unsigned short*)w; w += align256((size_t)Mpad * HID * 2);
    float* x1       = (float*)w; w += align256((size_t)N * HID * 4);
    float* h2       = (float*)w; w += align256((size_t)N * NCLS * 4);
    (void)ws_size;

    const int nB = (N + 1023) / 1024;
    const int eBlocks = (E + 255) / 256;
    const int nBlocks = (N + 255) / 256;
    const int waveBlocks = (N + 3) / 4;

    hipMemsetAsync(cnt, 0, (size_t)N * 4, stream);
    detect64_kernel<<<1, 256, 0, stream>>>(edge_index, flag64);
    count_kernel<<<eBlocks, 256, 0, stream>>>(edge_index, E, flag64, cnt);
    scan_block_sums<<<nB, 256, 0, stream>>>(cnt, blockSums, N);
    scan_sums_kernel<<<1, 64, 0, stream>>>(blockSums, nB, rowStart, N);
    dinv_kernel<<<nBlocks, 256, 0, stream>>>(cnt, dinv, N);
    scan_final<<<nB, 256, 0, stream>>>(cnt, blockSums, rowStart, rowPos, N);
    fill_kernel<<<eBlocks, 256, 0, stream>>>(edge_index, E, flag64, dinv, rowPos,
                                             csrSrc, csrNorm);

    // bf16 conversions (overlap-friendly, independent of CSR chain)
    {
        int tot = Mpad * F_IN, real = N * F_IN;
        convertX_kernel<<<(tot / 4 + 255) / 256, 256, 0, stream>>>(features, Xb, real, tot);
        convertW1t_kernel<<<(F_IN * HID) / 256, 256, 0, stream>>>(W1, W1t);
    }

    dim3 g1(Mpad / 128, HID / 128);
    gemm1_mfma_kernel<<<g1, 256, 0, stream>>>(Xb, W1t, h1);
    agg1_kernel<<<waveBlocks, 256, 0, stream>>>(h1, rowStart, csrSrc, csrNorm, dinv,
                                                b1, x1, N);
    gemm2_kernel<<<waveBlocks, 256, 0, stream>>>(x1, W2, h2, N);
    agg2_kernel<<<waveBlocks, 256, 0, stream>>>(h2, rowStart, csrSrc, csrNorm, dinv,
                                                b2, out, N);
}

// Round 3
// 912.813 us; speedup vs baseline: 1.8963x; 1.3559x over previous
//
#include <hip/hip_runtime.h>
#include <hip/hip_bf16.h>

// ---------------------------------------------------------------------------
// GCN 2-layer forward (f32 in/out), MFMA bf16 GEMMs:
//   x1 = relu( Ahat @ (X W1) + b1 ),  out = Ahat @ (x1 W2) + b2
//   return log_softmax(out), softmax(out)
// Round 3: GEMM2 also via mfma_f32_16x16x32_bf16 (N padded 40->48, W2
// transposed n-major, x1 stored bf16 by agg1). A-frags straight from global,
// B L1-resident. Replaces the 376us latency-bound wave-per-node gemm2.
// ---------------------------------------------------------------------------

#define F_IN 512
#define HID  256
#define NCLS 40
#define NPAD 48

typedef __attribute__((ext_vector_type(8))) short bf16x8;
typedef __attribute__((ext_vector_type(4))) float floatx4;

__device__ inline unsigned short f2bf(float v) {
    unsigned u = __float_as_uint(v);
    u += 0x7fffu + ((u >> 16) & 1u);   // round-to-nearest-even
    return (unsigned short)(u >> 16);
}
__device__ inline float bf2f(unsigned short u) {
    return __uint_as_float(((unsigned)u) << 16);
}

// ---------------- edge dtype detect (int64 vs int32) ----------------
__global__ void detect64_kernel(const int* __restrict__ ei, int* __restrict__ flag) {
    __shared__ int any_nz;
    if (threadIdx.x == 0) any_nz = 0;
    __syncthreads();
    int nz = 0;
    for (int i = threadIdx.x; i < 4096; i += 256) {
        nz |= (ei[2 * i + 1] != 0);
    }
    if (nz) atomicOr(&any_nz, 1);
    __syncthreads();
    if (threadIdx.x == 0) *flag = any_nz ? 0 : 1;  // 1 => int64 layout
}

__device__ inline int edge_src(const int* ei, long long E, int e, int is64) {
    return is64 ? ei[2LL * e] : ei[e];
}
__device__ inline int edge_dst(const int* ei, long long E, int e, int is64) {
    return is64 ? ei[2LL * (E + e)] : ei[(int)E + e];
}

// ---------------- degree count ----------------
__global__ void count_kernel(const int* __restrict__ ei, int E,
                             const int* __restrict__ flag, int* __restrict__ cnt) {
    int e = blockIdx.x * 256 + threadIdx.x;
    if (e >= E) return;
    int is64 = *flag;
    int d = edge_dst(ei, E, e, is64);
    atomicAdd(&cnt[d], 1);
}

// ---------------- scan (3-phase) ----------------
__global__ __launch_bounds__(256) void scan_block_sums(const int* __restrict__ cnt,
                                                       int* __restrict__ blockSums, int Nn) {
    __shared__ int sdata[256];
    int b = blockIdx.x, t = threadIdx.x;
    int sum = 0;
    int i0 = b * 1024 + t * 4;
    for (int i = 0; i < 4; ++i) {
        int idx = i0 + i;
        if (idx < Nn) sum += cnt[idx];
    }
    sdata[t] = sum;
    __syncthreads();
    for (int s = 128; s > 0; s >>= 1) {
        if (t < s) sdata[t] += sdata[t + s];
        __syncthreads();
    }
    if (t == 0) blockSums[b] = sdata[0];
}

__global__ void scan_sums_kernel(int* __restrict__ blockSums, int nB,
                                 int* __restrict__ rowStart, int Nn) {
    if (threadIdx.x == 0 && blockIdx.x == 0) {
        int run = 0;
        for (int i = 0; i < nB; ++i) { int v = blockSums[i]; blockSums[i] = run; run += v; }
        rowStart[Nn] = run;  // == E
    }
}

__global__ __launch_bounds__(256) void scan_final(const int* __restrict__ cnt,
                                                  const int* __restrict__ blockSumsEx,
                                                  int* __restrict__ rowStart,
                                                  int* __restrict__ rowPos, int Nn) {
    __shared__ int sdata[256];
    int b = blockIdx.x, t = threadIdx.x;
    int base = blockSumsEx[b];
    int vals[4];
    int sum = 0;
    int i0 = b * 1024 + t * 4;
    for (int i = 0; i < 4; ++i) {
        int idx = i0 + i;
        vals[i] = (idx < Nn) ? cnt[idx] : 0;
        sum += vals[i];
    }
    sdata[t] = sum;
    __syncthreads();
    for (int off = 1; off < 256; off <<= 1) {
        int y = (t >= off) ? sdata[t - off] : 0;
        __syncthreads();
        sdata[t] += y;
        __syncthreads();
    }
    int run = base + (sdata[t] - sum);  // exclusive
    for (int i = 0; i < 4; ++i) {
        int idx = i0 + i;
        if (idx < Nn) { rowStart[idx] = run; rowPos[idx] = run; }
        run += vals[i];
    }
}

// ---------------- dinv ----------------
__global__ void dinv_kernel(const int* __restrict__ cnt, float* __restrict__ dinv, int Nn) {
    int i = blockIdx.x * 256 + threadIdx.x;
    if (i < Nn) dinv[i] = rsqrtf((float)cnt[i] + 1.0f);
}

// ---------------- CSR fill (+norm precompute) ----------------
__global__ void fill_kernel(const int* __restrict__ ei, int E, const int* __restrict__ flag,
                            const float* __restrict__ dinv, int* __restrict__ rowPos,
                            int* __restrict__ csrSrc, float* __restrict__ csrNorm) {
    int e = blockIdx.x * 256 + threadIdx.x;
    if (e >= E) return;
    int is64 = *flag;
    int s = edge_src(ei, E, e, is64);
    int d = edge_dst(ei, E, e, is64);
    int p = atomicAdd(&rowPos[d], 1);
    csrSrc[p] = s;
    csrNorm[p] = dinv[s] * dinv[d];
}

// ---------------- bf16 conversions ----------------
__global__ __launch_bounds__(256) void convertX_kernel(const float* __restrict__ X,
                                                       unsigned short* __restrict__ Xb,
                                                       int realElems, int totElems) {
    int i = (blockIdx.x * 256 + threadIdx.x) * 4;
    if (i >= totElems) return;
    float4 v = make_float4(0.f, 0.f, 0.f, 0.f);
    if (i < realElems) v = *(const float4*)&X[i];
    ushort4 o;
    o.x = f2bf(v.x); o.y = f2bf(v.y); o.z = f2bf(v.z); o.w = f2bf(v.w);
    *(ushort4*)&Xb[i] = o;
}

// W1 [512,256] f32 -> W1t [256,512] bf16 (n-major)
__global__ __launch_bounds__(256) void convertW1t_kernel(const float* __restrict__ W1,
                                                         unsigned short* __restrict__ W1t) {
    int id = blockIdx.x * 256 + threadIdx.x;  // 512*256
    int k = id >> 8, n = id & 255;
    W1t[n * 512 + k] = f2bf(W1[id]);
}

// W2 [256,40] f32 -> W2t [48,256] bf16 (n-major, zero-padded n>=40)
__global__ __launch_bounds__(256) void convertW2t_kernel(const float* __restrict__ W2,
                                                         unsigned short* __restrict__ W2t) {
    int id = blockIdx.x * 256 + threadIdx.x;  // 48*256
    if (id >= NPAD * HID) return;
    int n = id / HID, k = id % HID;
    W2t[id] = (n < NCLS) ? f2bf(W2[k * NCLS + n]) : (unsigned short)0;
}

// ---------------- GEMM1 MFMA: h1[Mpad,256](bf16) = Xb @ W1t^T ---------------
#define LDK 40
__global__ __launch_bounds__(256) void gemm1_mfma_kernel(const unsigned short* __restrict__ Xb,
                                                         const unsigned short* __restrict__ W1t,
                                                         unsigned short* __restrict__ h1) {
    __shared__ unsigned short As[128][LDK];
    __shared__ unsigned short Bs[128][LDK];
    const int tid = threadIdx.x;
    const int bm = blockIdx.x * 128;
    const int bn = blockIdx.y * 128;
    const int lane = tid & 63, w = tid >> 6;
    const int mblk = (w & 1) * 64, nblk = (w >> 1) * 64;
    const int lrow = lane & 15, lq = lane >> 4;

    floatx4 acc[4][4];
#pragma unroll
    for (int i = 0; i < 4; ++i)
#pragma unroll
        for (int j = 0; j < 4; ++j)
            acc[i][j] = (floatx4){0.f, 0.f, 0.f, 0.f};

    for (int k0 = 0; k0 < F_IN; k0 += 32) {
#pragma unroll
        for (int i = 0; i < 2; ++i) {
            int c = tid + i * 256;
            int row = c >> 2, kb = (c & 3) * 8;
            *(float4*)&As[row][kb] =
                *(const float4*)&Xb[(size_t)(bm + row) * F_IN + k0 + kb];
            *(float4*)&Bs[row][kb] =
                *(const float4*)&W1t[(size_t)(bn + row) * F_IN + k0 + kb];
        }
        __syncthreads();
        bf16x8 a[4], b[4];
#pragma unroll
        for (int mt = 0; mt < 4; ++mt)
            a[mt] = *(const bf16x8*)&As[mblk + mt * 16 + lrow][lq * 8];
#pragma unroll
        for (int nt = 0; nt < 4; ++nt)
            b[nt] = *(const bf16x8*)&Bs[nblk + nt * 16 + lrow][lq * 8];
#pragma unroll
        for (int mt = 0; mt < 4; ++mt)
#pragma unroll
            for (int nt = 0; nt < 4; ++nt)
                acc[mt][nt] = __builtin_amdgcn_mfma_f32_16x16x32_bf16(
                    a[mt], b[nt], acc[mt][nt], 0, 0, 0);
        __syncthreads();
    }
#pragma unroll
    for (int mt = 0; mt < 4; ++mt) {
#pragma unroll
        for (int nt = 0; nt < 4; ++nt) {
            int gn = bn + nblk + nt * 16 + lrow;
            size_t gm0 = (size_t)(bm + mblk + mt * 16 + lq * 4);
#pragma unroll
            for (int r = 0; r < 4; ++r)
                h1[(gm0 + r) * HID + gn] = f2bf(acc[mt][nt][r]);
        }
    }
}

// ---------------- Agg1 + bias + relu: wave per node, bf16 in/out -----------
__global__ __launch_bounds__(256) void agg1_kernel(const unsigned short* __restrict__ h1,
                                                   const int* __restrict__ rowStart,
                                                   const int* __restrict__ csrSrc,
                                                   const float* __restrict__ csrNorm,
                                                   const float* __restrict__ dinv,
                                                   const float* __restrict__ b1,
                                                   unsigned short* __restrict__ x1b, int Nn) {
    int n = blockIdx.x * 4 + (threadIdx.x >> 6);
    int lane = threadIdx.x & 63;
    if (n >= Nn) return;
    float4 acc = make_float4(0.f, 0.f, 0.f, 0.f);
    int s0 = rowStart[n], s1 = rowStart[n + 1];
    for (int e = s0; e < s1; ++e) {
        int s = csrSrc[e];
        float nrm = csrNorm[e];
        ushort4 v = *(const ushort4*)(h1 + (size_t)s * HID + lane * 4);
        acc.x += nrm * bf2f(v.x);
        acc.y += nrm * bf2f(v.y);
        acc.z += nrm * bf2f(v.z);
        acc.w += nrm * bf2f(v.w);
    }
    float di = dinv[n];
    float self = di * di;
    ushort4 hv = *(const ushort4*)(h1 + (size_t)n * HID + lane * 4);
    float4 bv = *(const float4*)(b1 + lane * 4);
    ushort4 o;
    o.x = f2bf(fmaxf(acc.x + self * bf2f(hv.x) + bv.x, 0.f));
    o.y = f2bf(fmaxf(acc.y + self * bf2f(hv.y) + bv.y, 0.f));
    o.z = f2bf(fmaxf(acc.z + self * bf2f(hv.z) + bv.z, 0.f));
    o.w = f2bf(fmaxf(acc.w + self * bf2f(hv.w) + bv.w, 0.f));
    *(ushort4*)(x1b + (size_t)n * HID + lane * 4) = o;
}

// ---------------- GEMM2 MFMA: h2[M,40](f32) = x1b @ W2t^T ------------------
// Block = 4 waves, 128 rows (wave w -> rows bm+w*32). Per wave: 2 m-frags x
// 3 n-frags, K=256 in 8 steps. A-frags from global (row-major bf16), B-frags
// from global (W2t 24KB, L1-resident). No LDS.
__global__ __launch_bounds__(256) void gemm2_mfma_kernel(const unsigned short* __restrict__ x1b,
                                                         const unsigned short* __restrict__ W2t,
                                                         float* __restrict__ h2, int Nn) {
    const int tid = threadIdx.x;
    const int lane = tid & 63, w = tid >> 6;
    const int base = blockIdx.x * 128 + w * 32;
    const int lrow = lane & 15, lq = lane >> 4;

    floatx4 acc[2][3];
#pragma unroll
    for (int i = 0; i < 2; ++i)
#pragma unroll
        for (int j = 0; j < 3; ++j)
            acc[i][j] = (floatx4){0.f, 0.f, 0.f, 0.f};

#pragma unroll
    for (int k0 = 0; k0 < HID; k0 += 32) {
        bf16x8 a[2], b[3];
#pragma unroll
        for (int mt = 0; mt < 2; ++mt)
            a[mt] = *(const bf16x8*)&x1b[(size_t)(base + mt * 16 + lrow) * HID + k0 + lq * 8];
#pragma unroll
        for (int nt = 0; nt < 3; ++nt)
            b[nt] = *(const bf16x8*)&W2t[(size_t)(nt * 16 + lrow) * HID + k0 + lq * 8];
#pragma unroll
        for (int mt = 0; mt < 2; ++mt)
#pragma unroll
            for (int nt = 0; nt < 3; ++nt)
                acc[mt][nt] = __builtin_amdgcn_mfma_f32_16x16x32_bf16(
                    a[mt], b[nt], acc[mt][nt], 0, 0, 0);
    }
#pragma unroll
    for (int mt = 0; mt < 2; ++mt) {
#pragma unroll
        for (int nt = 0; nt < 3; ++nt) {
            int gn = nt * 16 + lrow;
            int gm0 = base + mt * 16 + lq * 4;
            if (gn < NCLS) {
#pragma unroll
                for (int r = 0; r < 4; ++r) {
                    int gm = gm0 + r;
                    if (gm < Nn) h2[(size_t)gm * NCLS + gn] = acc[mt][nt][r];
                }
            }
        }
    }
}

// ---------------- Agg2 + bias + softmax/log_softmax ------------------------
__global__ __launch_bounds__(256) void agg2_kernel(const float* __restrict__ h2,
                                                   const int* __restrict__ rowStart,
                                                   const int* __restrict__ csrSrc,
                                                   const float* __restrict__ csrNorm,
                                                   const float* __restrict__ dinv,
                                                   const float* __restrict__ b2,
                                                   float* __restrict__ out, int Nn) {
    int n = blockIdx.x * 4 + (threadIdx.x >> 6);
    int lane = threadIdx.x & 63;
    if (n >= Nn) return;
    bool act = lane < NCLS;
    float acc = 0.f;
    int s0 = rowStart[n], s1 = rowStart[n + 1];
    for (int e = s0; e < s1; ++e) {
        int s = csrSrc[e];
        float nrm = csrNorm[e];
        if (act) acc += nrm * h2[(size_t)s * NCLS + lane];
    }
    float di = dinv[n];
    if (act) acc += di * di * h2[(size_t)n * NCLS + lane] + b2[lane];
    float v = act ? acc : -3.4e38f;
#pragma unroll
    for (int off = 32; off > 0; off >>= 1) v = fmaxf(v, __shfl_xor(v, off));
    float ex = act ? expf(acc - v) : 0.f;
    float ssum = ex;
#pragma unroll
    for (int off = 32; off > 0; off >>= 1) ssum += __shfl_xor(ssum, off);
    if (act) {
        float ls = acc - v - logf(ssum);
        out[(size_t)n * NCLS + lane] = ls;                             // log_softmax
        out[(size_t)Nn * NCLS + (size_t)n * NCLS + lane] = ex / ssum;  // softmax
    }
}

// ---------------------------------------------------------------------------
extern "C" void kernel_launch(void* const* d_in, const int* in_sizes, int n_in,
                              void* d_out, int out_size, void* d_ws, size_t ws_size,
                              hipStream_t stream) {
    const float* features = (const float*)d_in[0];
    const float* W1 = (const float*)d_in[1];
    const float* b1 = (const float*)d_in[2];
    const float* W2 = (const float*)d_in[3];
    const float* b2 = (const float*)d_in[4];
    const int* edge_index = (const int*)d_in[5];

    const int N = in_sizes[0] / F_IN;        // 100000
    const int E = in_sizes[5] / 2;           // 1600000
    const int Mpad = (N + 127) & ~127;       // 100096
    float* out = (float*)d_out;

    auto align256 = [](size_t x) { return (x + 255) & ~(size_t)255; };
    char* w = (char*)d_ws;
    int* cnt        = (int*)w;  w += align256((size_t)N * 4);
    int* rowStart   = (int*)w;  w += align256((size_t)(N + 1) * 4);
    int* rowPos     = (int*)w;  w += align256((size_t)N * 4);
    int* blockSums  = (int*)w;  w += align256(1024 * 4);
    int* flag64     = (int*)w;  w += 256;
    int* csrSrc     = (int*)w;  w += align256((size_t)E * 4);
    float* csrNorm  = (float*)w; w += align256((size_t)E * 4);
    float* dinv     = (float*)w; w += align256((size_t)N * 4);
    unsigned short* Xb  = (unsigned short*)w; w += align256((size_t)Mpad * F_IN * 2);
    unsigned short* W1t = (unsigned short*)w; w += align256((size_t)HID * F_IN * 2);
    unsigned short* W2t = (unsigned short*)w; w += align256((size_t)NPAD * HID * 2);
    unsigned short* h1  = (unsigned short*)w; w += align256((size_t)Mpad * HID * 2);
    unsigned short* x1b = (unsigned short*)w; w += align256((size_t)Mpad * HID * 2);
    float* h2       = (float*)w; w += align256((size_t)N * NCLS * 4);
    (void)ws_size;

    const int nB = (N + 1023) / 1024;
    const int eBlocks = (E + 255) / 256;
    const int nBlocks = (N + 255) / 256;
    const int waveBlocks = (N + 3) / 4;

    hipMemsetAsync(cnt, 0, (size_t)N * 4, stream);
    detect64_kernel<<<1, 256, 0, stream>>>(edge_index, flag64);
    count_kernel<<<eBlocks, 256, 0, stream>>>(edge_index, E, flag64, cnt);
    scan_block_sums<<<nB, 256, 0, stream>>>(cnt, blockSums, N);
    scan_sums_kernel<<<1, 64, 0, stream>>>(blockSums, nB, rowStart, N);
    dinv_kernel<<<nBlocks, 256, 0, stream>>>(cnt, dinv, N);
    scan_final<<<nB, 256, 0, stream>>>(cnt, blockSums, rowStart, rowPos, N);
    fill_kernel<<<eBlocks, 256, 0, stream>>>(edge_index, E, flag64, dinv, rowPos,
                                             csrSrc, csrNorm);

    {
        int tot = Mpad * F_IN, real = N * F_IN;
        convertX_kernel<<<(tot / 4 + 255) / 256, 256, 0, stream>>>(features, Xb, real, tot);
        convertW1t_kernel<<<(F_IN * HID) / 256, 256, 0, stream>>>(W1, W1t);
        convertW2t_kernel<<<(NPAD * HID + 255) / 256, 256, 0, stream>>>(W2, W2t);
    }

    dim3 g1(Mpad / 128, HID / 128);
    gemm1_mfma_kernel<<<g1, 256, 0, stream>>>(Xb, W1t, h1);
    agg1_kernel<<<waveBlocks, 256, 0, stream>>>(h1, rowStart, csrSrc, csrNorm, dinv,
                                                b1, x1b, N);
    gemm2_mfma_kernel<<<Mpad / 128, 256, 0, stream>>>(x1b, W2t, h2, N);
    agg2_kernel<<<waveBlocks, 256, 0, stream>>>(h2, rowStart, csrSrc, csrNorm, dinv,
                                                b2, out, N);
}

// Round 4
// 786.809 us; speedup vs baseline: 2.2000x; 1.1601x over previous
//
#include <hip/hip_runtime.h>
#include <hip/hip_bf16.h>

// ---------------------------------------------------------------------------
// GCN 2-layer forward (f32 in/out), MFMA bf16 GEMMs:
//   x1 = relu( Ahat @ (X W1) + b1 ),  out = Ahat @ (x1 W2) + b2
//   return log_softmax(out), softmax(out)
// Round 4: (1) agg1/agg2 unrolled x4 (independent row loads in flight --
// they were gather-latency-bound at 23% VALUBusy); (2) convertX eliminated:
// gemm1 stages A from f32 global with in-register bf16 convert; (3) h2 kept
// bf16 at row stride 48 (half the agg2 gather bytes, <=2 lines/row).
// ---------------------------------------------------------------------------

#define F_IN 512
#define HID  256
#define NCLS 40
#define NPAD 48

typedef __attribute__((ext_vector_type(8))) short bf16x8;
typedef __attribute__((ext_vector_type(4))) float floatx4;

__device__ inline unsigned short f2bf(float v) {
    unsigned u = __float_as_uint(v);
    u += 0x7fffu + ((u >> 16) & 1u);   // round-to-nearest-even
    return (unsigned short)(u >> 16);
}
__device__ inline float bf2f(unsigned short u) {
    return __uint_as_float(((unsigned)u) << 16);
}

// ---------------- edge dtype detect (int64 vs int32) ----------------
__global__ void detect64_kernel(const int* __restrict__ ei, int* __restrict__ flag) {
    __shared__ int any_nz;
    if (threadIdx.x == 0) any_nz = 0;
    __syncthreads();
    int nz = 0;
    for (int i = threadIdx.x; i < 4096; i += 256) {
        nz |= (ei[2 * i + 1] != 0);
    }
    if (nz) atomicOr(&any_nz, 1);
    __syncthreads();
    if (threadIdx.x == 0) *flag = any_nz ? 0 : 1;  // 1 => int64 layout
}

__device__ inline int edge_src(const int* ei, long long E, int e, int is64) {
    return is64 ? ei[2LL * e] : ei[e];
}
__device__ inline int edge_dst(const int* ei, long long E, int e, int is64) {
    return is64 ? ei[2LL * (E + e)] : ei[(int)E + e];
}

// ---------------- degree count ----------------
__global__ void count_kernel(const int* __restrict__ ei, int E,
                             const int* __restrict__ flag, int* __restrict__ cnt) {
    int e = blockIdx.x * 256 + threadIdx.x;
    if (e >= E) return;
    int is64 = *flag;
    int d = edge_dst(ei, E, e, is64);
    atomicAdd(&cnt[d], 1);
}

// ---------------- scan (3-phase) ----------------
__global__ __launch_bounds__(256) void scan_block_sums(const int* __restrict__ cnt,
                                                       int* __restrict__ blockSums, int Nn) {
    __shared__ int sdata[256];
    int b = blockIdx.x, t = threadIdx.x;
    int sum = 0;
    int i0 = b * 1024 + t * 4;
    for (int i = 0; i < 4; ++i) {
        int idx = i0 + i;
        if (idx < Nn) sum += cnt[idx];
    }
    sdata[t] = sum;
    __syncthreads();
    for (int s = 128; s > 0; s >>= 1) {
        if (t < s) sdata[t] += sdata[t + s];
        __syncthreads();
    }
    if (t == 0) blockSums[b] = sdata[0];
}

__global__ void scan_sums_kernel(int* __restrict__ blockSums, int nB,
                                 int* __restrict__ rowStart, int Nn) {
    if (threadIdx.x == 0 && blockIdx.x == 0) {
        int run = 0;
        for (int i = 0; i < nB; ++i) { int v = blockSums[i]; blockSums[i] = run; run += v; }
        rowStart[Nn] = run;  // == E
    }
}

__global__ __launch_bounds__(256) void scan_final(const int* __restrict__ cnt,
                                                  const int* __restrict__ blockSumsEx,
                                                  int* __restrict__ rowStart,
                                                  int* __restrict__ rowPos, int Nn) {
    __shared__ int sdata[256];
    int b = blockIdx.x, t = threadIdx.x;
    int base = blockSumsEx[b];
    int vals[4];
    int sum = 0;
    int i0 = b * 1024 + t * 4;
    for (int i = 0; i < 4; ++i) {
        int idx = i0 + i;
        vals[i] = (idx < Nn) ? cnt[idx] : 0;
        sum += vals[i];
    }
    sdata[t] = sum;
    __syncthreads();
    for (int off = 1; off < 256; off <<= 1) {
        int y = (t >= off) ? sdata[t - off] : 0;
        __syncthreads();
        sdata[t] += y;
        __syncthreads();
    }
    int run = base + (sdata[t] - sum);  // exclusive
    for (int i = 0; i < 4; ++i) {
        int idx = i0 + i;
        if (idx < Nn) { rowStart[idx] = run; rowPos[idx] = run; }
        run += vals[i];
    }
}

// ---------------- dinv ----------------
__global__ void dinv_kernel(const int* __restrict__ cnt, float* __restrict__ dinv, int Nn) {
    int i = blockIdx.x * 256 + threadIdx.x;
    if (i < Nn) dinv[i] = rsqrtf((float)cnt[i] + 1.0f);
}

// ---------------- CSR fill (+norm precompute) ----------------
__global__ void fill_kernel(const int* __restrict__ ei, int E, const int* __restrict__ flag,
                            const float* __restrict__ dinv, int* __restrict__ rowPos,
                            int* __restrict__ csrSrc, float* __restrict__ csrNorm) {
    int e = blockIdx.x * 256 + threadIdx.x;
    if (e >= E) return;
    int is64 = *flag;
    int s = edge_src(ei, E, e, is64);
    int d = edge_dst(ei, E, e, is64);
    int p = atomicAdd(&rowPos[d], 1);
    csrSrc[p] = s;
    csrNorm[p] = dinv[s] * dinv[d];
}

// ---------------- weight conversions ----------------
// W1 [512,256] f32 -> W1t [256,512] bf16 (n-major)
__global__ __launch_bounds__(256) void convertW1t_kernel(const float* __restrict__ W1,
                                                         unsigned short* __restrict__ W1t) {
    int id = blockIdx.x * 256 + threadIdx.x;  // 512*256
    int k = id >> 8, n = id & 255;
    W1t[n * 512 + k] = f2bf(W1[id]);
}

// W2 [256,40] f32 -> W2t [48,256] bf16 (n-major, zero-padded n>=40)
__global__ __launch_bounds__(256) void convertW2t_kernel(const float* __restrict__ W2,
                                                         unsigned short* __restrict__ W2t) {
    int id = blockIdx.x * 256 + threadIdx.x;  // 48*256
    if (id >= NPAD * HID) return;
    int n = id / HID, k = id % HID;
    W2t[id] = (n < NCLS) ? f2bf(W2[k * NCLS + n]) : (unsigned short)0;
}

// ---------------- GEMM1 MFMA: h1[Mpad,256](bf16) = bf16(X) @ W1t^T ----------
// A staged from f32 global with in-register bf16 convert (no convertX pass).
#define LDK 40
__global__ __launch_bounds__(256) void gemm1_mfma_kernel(const float* __restrict__ X,
                                                         const unsigned short* __restrict__ W1t,
                                                         unsigned short* __restrict__ h1, int Nn) {
    __shared__ unsigned short As[128][LDK];
    __shared__ unsigned short Bs[128][LDK];
    const int tid = threadIdx.x;
    const int bm = blockIdx.x * 128;
    const int bn = blockIdx.y * 128;
    const int lane = tid & 63, w = tid >> 6;
    const int mblk = (w & 1) * 64, nblk = (w >> 1) * 64;
    const int lrow = lane & 15, lq = lane >> 4;

    floatx4 acc[4][4];
#pragma unroll
    for (int i = 0; i < 4; ++i)
#pragma unroll
        for (int j = 0; j < 4; ++j)
            acc[i][j] = (floatx4){0.f, 0.f, 0.f, 0.f};

    for (int k0 = 0; k0 < F_IN; k0 += 32) {
        // A: 128 rows x 32 k from f32 (4096 floats = 1024 float4 chunks)
#pragma unroll
        for (int i = 0; i < 4; ++i) {
            int c = tid + i * 256;           // 0..1023
            int row = c >> 3, kb = (c & 7) * 4;
            int gm = bm + row;
            float4 v = make_float4(0.f, 0.f, 0.f, 0.f);
            if (gm < Nn) v = *(const float4*)&X[(size_t)gm * F_IN + k0 + kb];
            ushort4 o;
            o.x = f2bf(v.x); o.y = f2bf(v.y); o.z = f2bf(v.z); o.w = f2bf(v.w);
            *(ushort4*)&As[row][kb] = o;
        }
        // B: 128 rows x 32 k bf16 (512 chunks of 8 bf16)
#pragma unroll
        for (int i = 0; i < 2; ++i) {
            int c = tid + i * 256;
            int row = c >> 2, kb = (c & 3) * 8;
            *(float4*)&Bs[row][kb] =
                *(const float4*)&W1t[(size_t)(bn + row) * F_IN + k0 + kb];
        }
        __syncthreads();
        bf16x8 a[4], b[4];
#pragma unroll
        for (int mt = 0; mt < 4; ++mt)
            a[mt] = *(const bf16x8*)&As[mblk + mt * 16 + lrow][lq * 8];
#pragma unroll
        for (int nt = 0; nt < 4; ++nt)
            b[nt] = *(const bf16x8*)&Bs[nblk + nt * 16 + lrow][lq * 8];
#pragma unroll
        for (int mt = 0; mt < 4; ++mt)
#pragma unroll
            for (int nt = 0; nt < 4; ++nt)
                acc[mt][nt] = __builtin_amdgcn_mfma_f32_16x16x32_bf16(
                    a[mt], b[nt], acc[mt][nt], 0, 0, 0);
        __syncthreads();
    }
#pragma unroll
    for (int mt = 0; mt < 4; ++mt) {
#pragma unroll
        for (int nt = 0; nt < 4; ++nt) {
            int gn = bn + nblk + nt * 16 + lrow;
            size_t gm0 = (size_t)(bm + mblk + mt * 16 + lq * 4);
#pragma unroll
            for (int r = 0; r < 4; ++r)
                h1[(gm0 + r) * HID + gn] = f2bf(acc[mt][nt][r]);
        }
    }
}

// ---------------- Agg1 + bias + relu: wave per node, unroll x4 -------------
__global__ __launch_bounds__(256) void agg1_kernel(const unsigned short* __restrict__ h1,
                                                   const int* __restrict__ rowStart,
                                                   const int* __restrict__ csrSrc,
                                                   const float* __restrict__ csrNorm,
                                                   const float* __restrict__ dinv,
                                                   const float* __restrict__ b1,
                                                   unsigned short* __restrict__ x1b, int Nn) {
    int n = blockIdx.x * 4 + (threadIdx.x >> 6);
    int lane = threadIdx.x & 63;
    if (n >= Nn) return;
    float4 acc = make_float4(0.f, 0.f, 0.f, 0.f);
    int s0 = rowStart[n], s1 = rowStart[n + 1];
    int e = s0;
    for (; e + 3 < s1; e += 4) {
        int iA = csrSrc[e], iB = csrSrc[e + 1], iC = csrSrc[e + 2], iD = csrSrc[e + 3];
        float nA = csrNorm[e], nB = csrNorm[e + 1], nC = csrNorm[e + 2], nD = csrNorm[e + 3];
        ushort4 vA = *(const ushort4*)(h1 + (size_t)iA * HID + lane * 4);
        ushort4 vB = *(const ushort4*)(h1 + (size_t)iB * HID + lane * 4);
        ushort4 vC = *(const ushort4*)(h1 + (size_t)iC * HID + lane * 4);
        ushort4 vD = *(const ushort4*)(h1 + (size_t)iD * HID + lane * 4);
        acc.x += nA * bf2f(vA.x) + nB * bf2f(vB.x) + nC * bf2f(vC.x) + nD * bf2f(vD.x);
        acc.y += nA * bf2f(vA.y) + nB * bf2f(vB.y) + nC * bf2f(vC.y) + nD * bf2f(vD.y);
        acc.z += nA * bf2f(vA.z) + nB * bf2f(vB.z) + nC * bf2f(vC.z) + nD * bf2f(vD.z);
        acc.w += nA * bf2f(vA.w) + nB * bf2f(vB.w) + nC * bf2f(vC.w) + nD * bf2f(vD.w);
    }
    for (; e < s1; ++e) {
        int s = csrSrc[e];
        float nrm = csrNorm[e];
        ushort4 v = *(const ushort4*)(h1 + (size_t)s * HID + lane * 4);
        acc.x += nrm * bf2f(v.x);
        acc.y += nrm * bf2f(v.y);
        acc.z += nrm * bf2f(v.z);
        acc.w += nrm * bf2f(v.w);
    }
    float di = dinv[n];
    float self = di * di;
    ushort4 hv = *(const ushort4*)(h1 + (size_t)n * HID + lane * 4);
    float4 bv = *(const float4*)(b1 + lane * 4);
    ushort4 o;
    o.x = f2bf(fmaxf(acc.x + self * bf2f(hv.x) + bv.x, 0.f));
    o.y = f2bf(fmaxf(acc.y + self * bf2f(hv.y) + bv.y, 0.f));
    o.z = f2bf(fmaxf(acc.z + self * bf2f(hv.z) + bv.z, 0.f));
    o.w = f2bf(fmaxf(acc.w + self * bf2f(hv.w) + bv.w, 0.f));
    *(ushort4*)(x1b + (size_t)n * HID + lane * 4) = o;
}

// ---------------- GEMM2 MFMA: h2b[Mpad,48](bf16) = x1b @ W2t^T -------------
__global__ __launch_bounds__(256) void gemm2_mfma_kernel(const unsigned short* __restrict__ x1b,
                                                         const unsigned short* __restrict__ W2t,
                                                         unsigned short* __restrict__ h2b) {
    const int tid = threadIdx.x;
    const int lane = tid & 63, w = tid >> 6;
    const int base = blockIdx.x * 128 + w * 32;
    const int lrow = lane & 15, lq = lane >> 4;

    floatx4 acc[2][3];
#pragma unroll
    for (int i = 0; i < 2; ++i)
#pragma unroll
        for (int j = 0; j < 3; ++j)
            acc[i][j] = (floatx4){0.f, 0.f, 0.f, 0.f};

#pragma unroll
    for (int k0 = 0; k0 < HID; k0 += 32) {
        bf16x8 a[2], b[3];
#pragma unroll
        for (int mt = 0; mt < 2; ++mt)
            a[mt] = *(const bf16x8*)&x1b[(size_t)(base + mt * 16 + lrow) * HID + k0 + lq * 8];
#pragma unroll
        for (int nt = 0; nt < 3; ++nt)
            b[nt] = *(const bf16x8*)&W2t[(size_t)(nt * 16 + lrow) * HID + k0 + lq * 8];
#pragma unroll
        for (int mt = 0; mt < 2; ++mt)
#pragma unroll
            for (int nt = 0; nt < 3; ++nt)
                acc[mt][nt] = __builtin_amdgcn_mfma_f32_16x16x32_bf16(
                    a[mt], b[nt], acc[mt][nt], 0, 0, 0);
    }
#pragma unroll
    for (int mt = 0; mt < 2; ++mt) {
#pragma unroll
        for (int nt = 0; nt < 3; ++nt) {
            int gn = nt * 16 + lrow;
            int gm0 = base + mt * 16 + lq * 4;
#pragma unroll
            for (int r = 0; r < 4; ++r)
                h2b[(size_t)(gm0 + r) * NPAD + gn] = f2bf(acc[mt][nt][r]);
        }
    }
}

// ---------------- Agg2 + bias + softmax/log_softmax, unroll x4 -------------
__global__ __launch_bounds__(256) void agg2_kernel(const unsigned short* __restrict__ h2b,
                                                   const int* __restrict__ rowStart,
                                                   const int* __restrict__ csrSrc,
                                                   const float* __restrict__ csrNorm,
                                                   const float* __restrict__ dinv,
                                                   const float* __restrict__ b2,
                                                   float* __restrict__ out, int Nn) {
    int n = blockIdx.x * 4 + (threadIdx.x >> 6);
    int lane = threadIdx.x & 63;
    if (n >= Nn) return;
    bool act = lane < NCLS;
    int cl = act ? lane : 0;
    float acc = 0.f;
    int s0 = rowStart[n], s1 = rowStart[n + 1];
    int e = s0;
    for (; e + 3 < s1; e += 4) {
        int iA = csrSrc[e], iB = csrSrc[e + 1], iC = csrSrc[e + 2], iD = csrSrc[e + 3];
        float nA = csrNorm[e], nB = csrNorm[e + 1], nC = csrNorm[e + 2], nD = csrNorm[e + 3];
        float vA = bf2f(h2b[(size_t)iA * NPAD + cl]);
        float vB = bf2f(h2b[(size_t)iB * NPAD + cl]);
        float vC = bf2f(h2b[(size_t)iC * NPAD + cl]);
        float vD = bf2f(h2b[(size_t)iD * NPAD + cl]);
        acc += nA * vA + nB * vB + nC * vC + nD * vD;
    }
    for (; e < s1; ++e) {
        int s = csrSrc[e];
        acc += csrNorm[e] * bf2f(h2b[(size_t)s * NPAD + cl]);
    }
    float di = dinv[n];
    acc += di * di * bf2f(h2b[(size_t)n * NPAD + cl]) + b2[cl];
    float v = act ? acc : -3.4e38f;
#pragma unroll
    for (int off = 32; off > 0; off >>= 1) v = fmaxf(v, __shfl_xor(v, off));
    float ex = act ? expf(acc - v) : 0.f;
    float ssum = ex;
#pragma unroll
    for (int off = 32; off > 0; off >>= 1) ssum += __shfl_xor(ssum, off);
    if (act) {
        float ls = acc - v - logf(ssum);
        out[(size_t)n * NCLS + lane] = ls;                             // log_softmax
        out[(size_t)Nn * NCLS + (size_t)n * NCLS + lane] = ex / ssum;  // softmax
    }
}

// ---------------------------------------------------------------------------
extern "C" void kernel_launch(void* const* d_in, const int* in_sizes, int n_in,
                              void* d_out, int out_size, void* d_ws, size_t ws_size,
                              hipStream_t stream) {
    const float* features = (const float*)d_in[0];
    const float* W1 = (const float*)d_in[1];
    const float* b1 = (const float*)d_in[2];
    const float* W2 = (const float*)d_in[3];
    const float* b2 = (const float*)d_in[4];
    const int* edge_index = (const int*)d_in[5];

    const int N = in_sizes[0] / F_IN;        // 100000
    const int E = in_sizes[5] / 2;           // 1600000
    const int Mpad = (N + 127) & ~127;       // 100096
    float* out = (float*)d_out;

    auto align256 = [](size_t x) { return (x + 255) & ~(size_t)255; };
    char* w = (char*)d_ws;
    int* cnt        = (int*)w;  w += align256((size_t)N * 4);
    int* rowStart   = (int*)w;  w += align256((size_t)(N + 1) * 4);
    int* rowPos     = (int*)w;  w += align256((size_t)N * 4);
    int* blockSums  = (int*)w;  w += align256(1024 * 4);
    int* flag64     = (int*)w;  w += 256;
    int* csrSrc     = (int*)w;  w += align256((size_t)E * 4);
    float* csrNorm  = (float*)w; w += align256((size_t)E * 4);
    float* dinv     = (float*)w; w += align256((size_t)N * 4);
    unsigned short* W1t = (unsigned short*)w; w += align256((size_t)HID * F_IN * 2);
    unsigned short* W2t = (unsigned short*)w; w += align256((size_t)NPAD * HID * 2);
    unsigned short* h1  = (unsigned short*)w; w += align256((size_t)Mpad * HID * 2);
    unsigned short* x1b = (unsigned short*)w; w += align256((size_t)Mpad * HID * 2);
    unsigned short* h2b = (unsigned short*)w; w += align256((size_t)Mpad * NPAD * 2);
    (void)ws_size;

    const int nB = (N + 1023) / 1024;
    const int eBlocks = (E + 255) / 256;
    const int nBlocks = (N + 255) / 256;
    const int waveBlocks = (N + 3) / 4;

    hipMemsetAsync(cnt, 0, (size_t)N * 4, stream);
    detect64_kernel<<<1, 256, 0, stream>>>(edge_index, flag64);
    count_kernel<<<eBlocks, 256, 0, stream>>>(edge_index, E, flag64, cnt);
    scan_block_sums<<<nB, 256, 0, stream>>>(cnt, blockSums, N);
    scan_sums_kernel<<<1, 64, 0, stream>>>(blockSums, nB, rowStart, N);
    dinv_kernel<<<nBlocks, 256, 0, stream>>>(cnt, dinv, N);
    scan_final<<<nB, 256, 0, stream>>>(cnt, blockSums, rowStart, rowPos, N);
    fill_kernel<<<eBlocks, 256, 0, stream>>>(edge_index, E, flag64, dinv, rowPos,
                                             csrSrc, csrNorm);

    convertW1t_kernel<<<(F_IN * HID) / 256, 256, 0, stream>>>(W1, W1t);
    convertW2t_kernel<<<(NPAD * HID + 255) / 256, 256, 0, stream>>>(W2, W2t);

    dim3 g1(Mpad / 128, HID / 128);
    gemm1_mfma_kernel<<<g1, 256, 0, stream>>>(features, W1t, h1, N);
    agg1_kernel<<<waveBlocks, 256, 0, stream>>>(h1, rowStart, csrSrc, csrNorm, dinv,
                                                b1, x1b, N);
    gemm2_mfma_kernel<<<Mpad / 128, 256, 0, stream>>>(x1b, W2t, h2b);
    agg2_kernel<<<waveBlocks, 256, 0, stream>>>(h2b, rowStart, csrSrc, csrNorm, dinv,
                                                b2, out, N);
}

// Round 5
// 773.596 us; speedup vs baseline: 2.2376x; 1.0171x over previous
//
#include <hip/hip_runtime.h>
#include <hip/hip_bf16.h>

// ---------------------------------------------------------------------------
// GCN 2-layer forward (f32 in/out), MFMA bf16 GEMMs:
//   x1 = relu( Ahat @ (X W1) + b1 ),  out = Ahat @ (x1 W2) + b2
//   return log_softmax(out), softmax(out)
// Round 5: gemm1 software-pipelined -- staging loads for K-step k+1 are
// issued into registers before the MFMA section of step k (round 4 was
// global-latency-bound: loads issued right before the barrier consuming
// them; MfmaUtil 6%, VALUBusy 10%, 26% occupancy).
// ---------------------------------------------------------------------------

#define F_IN 512
#define HID  256
#define NCLS 40
#define NPAD 48

typedef __attribute__((ext_vector_type(8))) short bf16x8;
typedef __attribute__((ext_vector_type(4))) float floatx4;

__device__ inline unsigned short f2bf(float v) {
    unsigned u = __float_as_uint(v);
    u += 0x7fffu + ((u >> 16) & 1u);   // round-to-nearest-even
    return (unsigned short)(u >> 16);
}
__device__ inline float bf2f(unsigned short u) {
    return __uint_as_float(((unsigned)u) << 16);
}

// ---------------- edge dtype detect (int64 vs int32) ----------------
__global__ void detect64_kernel(const int* __restrict__ ei, int* __restrict__ flag) {
    __shared__ int any_nz;
    if (threadIdx.x == 0) any_nz = 0;
    __syncthreads();
    int nz = 0;
    for (int i = threadIdx.x; i < 4096; i += 256) {
        nz |= (ei[2 * i + 1] != 0);
    }
    if (nz) atomicOr(&any_nz, 1);
    __syncthreads();
    if (threadIdx.x == 0) *flag = any_nz ? 0 : 1;  // 1 => int64 layout
}

__device__ inline int edge_src(const int* ei, long long E, int e, int is64) {
    return is64 ? ei[2LL * e] : ei[e];
}
__device__ inline int edge_dst(const int* ei, long long E, int e, int is64) {
    return is64 ? ei[2LL * (E + e)] : ei[(int)E + e];
}

// ---------------- degree count ----------------
__global__ void count_kernel(const int* __restrict__ ei, int E,
                             const int* __restrict__ flag, int* __restrict__ cnt) {
    int e = blockIdx.x * 256 + threadIdx.x;
    if (e >= E) return;
    int is64 = *flag;
    int d = edge_dst(ei, E, e, is64);
    atomicAdd(&cnt[d], 1);
}

// ---------------- scan (3-phase) ----------------
__global__ __launch_bounds__(256) void scan_block_sums(const int* __restrict__ cnt,
                                                       int* __restrict__ blockSums, int Nn) {
    __shared__ int sdata[256];
    int b = blockIdx.x, t = threadIdx.x;
    int sum = 0;
    int i0 = b * 1024 + t * 4;
    for (int i = 0; i < 4; ++i) {
        int idx = i0 + i;
        if (idx < Nn) sum += cnt[idx];
    }
    sdata[t] = sum;
    __syncthreads();
    for (int s = 128; s > 0; s >>= 1) {
        if (t < s) sdata[t] += sdata[t + s];
        __syncthreads();
    }
    if (t == 0) blockSums[b] = sdata[0];
}

__global__ void scan_sums_kernel(int* __restrict__ blockSums, int nB,
                                 int* __restrict__ rowStart, int Nn) {
    if (threadIdx.x == 0 && blockIdx.x == 0) {
        int run = 0;
        for (int i = 0; i < nB; ++i) { int v = blockSums[i]; blockSums[i] = run; run += v; }
        rowStart[Nn] = run;  // == E
    }
}

__global__ __launch_bounds__(256) void scan_final(const int* __restrict__ cnt,
                                                  const int* __restrict__ blockSumsEx,
                                                  int* __restrict__ rowStart,
                                                  int* __restrict__ rowPos, int Nn) {
    __shared__ int sdata[256];
    int b = blockIdx.x, t = threadIdx.x;
    int base = blockSumsEx[b];
    int vals[4];
    int sum = 0;
    int i0 = b * 1024 + t * 4;
    for (int i = 0; i < 4; ++i) {
        int idx = i0 + i;
        vals[i] = (idx < Nn) ? cnt[idx] : 0;
        sum += vals[i];
    }
    sdata[t] = sum;
    __syncthreads();
    for (int off = 1; off < 256; off <<= 1) {
        int y = (t >= off) ? sdata[t - off] : 0;
        __syncthreads();
        sdata[t] += y;
        __syncthreads();
    }
    int run = base + (sdata[t] - sum);  // exclusive
    for (int i = 0; i < 4; ++i) {
        int idx = i0 + i;
        if (idx < Nn) { rowStart[idx] = run; rowPos[idx] = run; }
        run += vals[i];
    }
}

// ---------------- dinv ----------------
__global__ void dinv_kernel(const int* __restrict__ cnt, float* __restrict__ dinv, int Nn) {
    int i = blockIdx.x * 256 + threadIdx.x;
    if (i < Nn) dinv[i] = rsqrtf((float)cnt[i] + 1.0f);
}

// ---------------- CSR fill (+norm precompute) ----------------
__global__ void fill_kernel(const int* __restrict__ ei, int E, const int* __restrict__ flag,
                            const float* __restrict__ dinv, int* __restrict__ rowPos,
                            int* __restrict__ csrSrc, float* __restrict__ csrNorm) {
    int e = blockIdx.x * 256 + threadIdx.x;
    if (e >= E) return;
    int is64 = *flag;
    int s = edge_src(ei, E, e, is64);
    int d = edge_dst(ei, E, e, is64);
    int p = atomicAdd(&rowPos[d], 1);
    csrSrc[p] = s;
    csrNorm[p] = dinv[s] * dinv[d];
}

// ---------------- weight conversions ----------------
// W1 [512,256] f32 -> W1t [256,512] bf16 (n-major)
__global__ __launch_bounds__(256) void convertW1t_kernel(const float* __restrict__ W1,
                                                         unsigned short* __restrict__ W1t) {
    int id = blockIdx.x * 256 + threadIdx.x;  // 512*256
    int k = id >> 8, n = id & 255;
    W1t[n * 512 + k] = f2bf(W1[id]);
}

// W2 [256,40] f32 -> W2t [48,256] bf16 (n-major, zero-padded n>=40)
__global__ __launch_bounds__(256) void convertW2t_kernel(const float* __restrict__ W2,
                                                         unsigned short* __restrict__ W2t) {
    int id = blockIdx.x * 256 + threadIdx.x;  // 48*256
    if (id >= NPAD * HID) return;
    int n = id / HID, k = id % HID;
    W2t[id] = (n < NCLS) ? f2bf(W2[k * NCLS + n]) : (unsigned short)0;
}

// ---------------- GEMM1 MFMA: h1[Mpad,256](bf16) = bf16(X) @ W1t^T ----------
// Software-pipelined: staging for K-step k+1 is loaded into registers before
// the MFMA section of step k, so global latency overlaps compute.
#define LDK 40
__global__ __launch_bounds__(256) void gemm1_mfma_kernel(const float* __restrict__ X,
                                                         const unsigned short* __restrict__ W1t,
                                                         unsigned short* __restrict__ h1, int Nn) {
    __shared__ unsigned short As[128][LDK];
    __shared__ unsigned short Bs[128][LDK];
    const int tid = threadIdx.x;
    const int bm = blockIdx.x * 128;
    const int bn = blockIdx.y * 128;
    const int lane = tid & 63, w = tid >> 6;
    const int mblk = (w & 1) * 64, nblk = (w >> 1) * 64;
    const int lrow = lane & 15, lq = lane >> 4;

    // Per-thread staging coordinates (fixed across K-steps):
    // A: 4 chunks of float4:  c = tid+i*256, row=c>>3, kb=(c&7)*4
    // B: 2 chunks of 8 bf16:  c = tid+i*256, row=c>>2, kb=(c&3)*8
    int aRow[4], aKb[4], bRow[2], bKb[2];
#pragma unroll
    for (int i = 0; i < 4; ++i) {
        int c = tid + i * 256;
        aRow[i] = c >> 3; aKb[i] = (c & 7) * 4;
    }
#pragma unroll
    for (int i = 0; i < 2; ++i) {
        int c = tid + i * 256;
        bRow[i] = c >> 2; bKb[i] = (c & 3) * 8;
    }

    float4 aReg[4];
    float4 bReg[2];
    // prologue: load k0 = 0
#pragma unroll
    for (int i = 0; i < 4; ++i) {
        int gm = bm + aRow[i];
        aReg[i] = make_float4(0.f, 0.f, 0.f, 0.f);
        if (gm < Nn) aReg[i] = *(const float4*)&X[(size_t)gm * F_IN + aKb[i]];
    }
#pragma unroll
    for (int i = 0; i < 2; ++i)
        bReg[i] = *(const float4*)&W1t[(size_t)(bn + bRow[i]) * F_IN + bKb[i]];

    floatx4 acc[4][4];
#pragma unroll
    for (int i = 0; i < 4; ++i)
#pragma unroll
        for (int j = 0; j < 4; ++j)
            acc[i][j] = (floatx4){0.f, 0.f, 0.f, 0.f};

    for (int k0 = 0; k0 < F_IN; k0 += 32) {
        __syncthreads();   // previous iteration's fragment reads complete
        // register -> LDS (bf16 convert for A)
#pragma unroll
        for (int i = 0; i < 4; ++i) {
            ushort4 o;
            o.x = f2bf(aReg[i].x); o.y = f2bf(aReg[i].y);
            o.z = f2bf(aReg[i].z); o.w = f2bf(aReg[i].w);
            *(ushort4*)&As[aRow[i]][aKb[i]] = o;
        }
#pragma unroll
        for (int i = 0; i < 2; ++i)
            *(float4*)&Bs[bRow[i]][bKb[i]] = bReg[i];
        __syncthreads();

        // issue next K-step's staging loads (in flight during MFMAs)
        int k1 = k0 + 32;
        if (k1 < F_IN) {
#pragma unroll
            for (int i = 0; i < 4; ++i) {
                int gm = bm + aRow[i];
                aReg[i] = make_float4(0.f, 0.f, 0.f, 0.f);
                if (gm < Nn) aReg[i] = *(const float4*)&X[(size_t)gm * F_IN + k1 + aKb[i]];
            }
#pragma unroll
            for (int i = 0; i < 2; ++i)
                bReg[i] = *(const float4*)&W1t[(size_t)(bn + bRow[i]) * F_IN + k1 + bKb[i]];
        }

        bf16x8 a[4], b[4];
#pragma unroll
        for (int mt = 0; mt < 4; ++mt)
            a[mt] = *(const bf16x8*)&As[mblk + mt * 16 + lrow][lq * 8];
#pragma unroll
        for (int nt = 0; nt < 4; ++nt)
            b[nt] = *(const bf16x8*)&Bs[nblk + nt * 16 + lrow][lq * 8];
#pragma unroll
        for (int mt = 0; mt < 4; ++mt)
#pragma unroll
            for (int nt = 0; nt < 4; ++nt)
                acc[mt][nt] = __builtin_amdgcn_mfma_f32_16x16x32_bf16(
                    a[mt], b[nt], acc[mt][nt], 0, 0, 0);
    }
#pragma unroll
    for (int mt = 0; mt < 4; ++mt) {
#pragma unroll
        for (int nt = 0; nt < 4; ++nt) {
            int gn = bn + nblk + nt * 16 + lrow;
            size_t gm0 = (size_t)(bm + mblk + mt * 16 + lq * 4);
#pragma unroll
            for (int r = 0; r < 4; ++r)
                h1[(gm0 + r) * HID + gn] = f2bf(acc[mt][nt][r]);
        }
    }
}

// ---------------- Agg1 + bias + relu: wave per node, unroll x4 -------------
__global__ __launch_bounds__(256) void agg1_kernel(const unsigned short* __restrict__ h1,
                                                   const int* __restrict__ rowStart,
                                                   const int* __restrict__ csrSrc,
                                                   const float* __restrict__ csrNorm,
                                                   const float* __restrict__ dinv,
                                                   const float* __restrict__ b1,
                                                   unsigned short* __restrict__ x1b, int Nn) {
    int n = blockIdx.x * 4 + (threadIdx.x >> 6);
    int lane = threadIdx.x & 63;
    if (n >= Nn) return;
    float4 acc = make_float4(0.f, 0.f, 0.f, 0.f);
    int s0 = rowStart[n], s1 = rowStart[n + 1];
    int e = s0;
    for (; e + 3 < s1; e += 4) {
        int iA = csrSrc[e], iB = csrSrc[e + 1], iC = csrSrc[e + 2], iD = csrSrc[e + 3];
        float nA = csrNorm[e], nB = csrNorm[e + 1], nC = csrNorm[e + 2], nD = csrNorm[e + 3];
        ushort4 vA = *(const ushort4*)(h1 + (size_t)iA * HID + lane * 4);
        ushort4 vB = *(const ushort4*)(h1 + (size_t)iB * HID + lane * 4);
        ushort4 vC = *(const ushort4*)(h1 + (size_t)iC * HID + lane * 4);
        ushort4 vD = *(const ushort4*)(h1 + (size_t)iD * HID + lane * 4);
        acc.x += nA * bf2f(vA.x) + nB * bf2f(vB.x) + nC * bf2f(vC.x) + nD * bf2f(vD.x);
        acc.y += nA * bf2f(vA.y) + nB * bf2f(vB.y) + nC * bf2f(vC.y) + nD * bf2f(vD.y);
        acc.z += nA * bf2f(vA.z) + nB * bf2f(vB.z) + nC * bf2f(vC.z) + nD * bf2f(vD.z);
        acc.w += nA * bf2f(vA.w) + nB * bf2f(vB.w) + nC * bf2f(vC.w) + nD * bf2f(vD.w);
    }
    for (; e < s1; ++e) {
        int s = csrSrc[e];
        float nrm = csrNorm[e];
        ushort4 v = *(const ushort4*)(h1 + (size_t)s * HID + lane * 4);
        acc.x += nrm * bf2f(v.x);
        acc.y += nrm * bf2f(v.y);
        acc.z += nrm * bf2f(v.z);
        acc.w += nrm * bf2f(v.w);
    }
    float di = dinv[n];
    float self = di * di;
    ushort4 hv = *(const ushort4*)(h1 + (size_t)n * HID + lane * 4);
    float4 bv = *(const float4*)(b1 + lane * 4);
    ushort4 o;
    o.x = f2bf(fmaxf(acc.x + self * bf2f(hv.x) + bv.x, 0.f));
    o.y = f2bf(fmaxf(acc.y + self * bf2f(hv.y) + bv.y, 0.f));
    o.z = f2bf(fmaxf(acc.z + self * bf2f(hv.z) + bv.z, 0.f));
    o.w = f2bf(fmaxf(acc.w + self * bf2f(hv.w) + bv.w, 0.f));
    *(ushort4*)(x1b + (size_t)n * HID + lane * 4) = o;
}

// ---------------- GEMM2 MFMA: h2b[Mpad,48](bf16) = x1b @ W2t^T -------------
__global__ __launch_bounds__(256) void gemm2_mfma_kernel(const unsigned short* __restrict__ x1b,
                                                         const unsigned short* __restrict__ W2t,
                                                         unsigned short* __restrict__ h2b) {
    const int tid = threadIdx.x;
    const int lane = tid & 63, w = tid >> 6;
    const int base = blockIdx.x * 128 + w * 32;
    const int lrow = lane & 15, lq = lane >> 4;

    floatx4 acc[2][3];
#pragma unroll
    for (int i = 0; i < 2; ++i)
#pragma unroll
        for (int j = 0; j < 3; ++j)
            acc[i][j] = (floatx4){0.f, 0.f, 0.f, 0.f};

#pragma unroll
    for (int k0 = 0; k0 < HID; k0 += 32) {
        bf16x8 a[2], b[3];
#pragma unroll
        for (int mt = 0; mt < 2; ++mt)
            a[mt] = *(const bf16x8*)&x1b[(size_t)(base + mt * 16 + lrow) * HID + k0 + lq * 8];
#pragma unroll
        for (int nt = 0; nt < 3; ++nt)
            b[nt] = *(const bf16x8*)&W2t[(size_t)(nt * 16 + lrow) * HID + k0 + lq * 8];
#pragma unroll
        for (int mt = 0; mt < 2; ++mt)
#pragma unroll
            for (int nt = 0; nt < 3; ++nt)
                acc[mt][nt] = __builtin_amdgcn_mfma_f32_16x16x32_bf16(
                    a[mt], b[nt], acc[mt][nt], 0, 0, 0);
    }
#pragma unroll
    for (int mt = 0; mt < 2; ++mt) {
#pragma unroll
        for (int nt = 0; nt < 3; ++nt) {
            int gn = nt * 16 + lrow;
            int gm0 = base + mt * 16 + lq * 4;
#pragma unroll
            for (int r = 0; r < 4; ++r)
                h2b[(size_t)(gm0 + r) * NPAD + gn] = f2bf(acc[mt][nt][r]);
        }
    }
}

// ---------------- Agg2 + bias + softmax/log_softmax, unroll x4 -------------
__global__ __launch_bounds__(256) void agg2_kernel(const unsigned short* __restrict__ h2b,
                                                   const int* __restrict__ rowStart,
                                                   const int* __restrict__ csrSrc,
                                                   const float* __restrict__ csrNorm,
                                                   const float* __restrict__ dinv,
                                                   const float* __restrict__ b2,
                                                   float* __restrict__ out, int Nn) {
    int n = blockIdx.x * 4 + (threadIdx.x >> 6);
    int lane = threadIdx.x & 63;
    if (n >= Nn) return;
    bool act = lane < NCLS;
    int cl = act ? lane : 0;
    float acc = 0.f;
    int s0 = rowStart[n], s1 = rowStart[n + 1];
    int e = s0;
    for (; e + 3 < s1; e += 4) {
        int iA = csrSrc[e], iB = csrSrc[e + 1], iC = csrSrc[e + 2], iD = csrSrc[e + 3];
        float nA = csrNorm[e], nB = csrNorm[e + 1], nC = csrNorm[e + 2], nD = csrNorm[e + 3];
        float vA = bf2f(h2b[(size_t)iA * NPAD + cl]);
        float vB = bf2f(h2b[(size_t)iB * NPAD + cl]);
        float vC = bf2f(h2b[(size_t)iC * NPAD + cl]);
        float vD = bf2f(h2b[(size_t)iD * NPAD + cl]);
        acc += nA * vA + nB * vB + nC * vC + nD * vD;
    }
    for (; e < s1; ++e) {
        int s = csrSrc[e];
        acc += csrNorm[e] * bf2f(h2b[(size_t)s * NPAD + cl]);
    }
    float di = dinv[n];
    acc += di * di * bf2f(h2b[(size_t)n * NPAD + cl]) + b2[cl];
    float v = act ? acc : -3.4e38f;
#pragma unroll
    for (int off = 32; off > 0; off >>= 1) v = fmaxf(v, __shfl_xor(v, off));
    float ex = act ? expf(acc - v) : 0.f;
    float ssum = ex;
#pragma unroll
    for (int off = 32; off > 0; off >>= 1) ssum += __shfl_xor(ssum, off);
    if (act) {
        float ls = acc - v - logf(ssum);
        out[(size_t)n * NCLS + lane] = ls;                             // log_softmax
        out[(size_t)Nn * NCLS + (size_t)n * NCLS + lane] = ex / ssum;  // softmax
    }
}

// ---------------------------------------------------------------------------
extern "C" void kernel_launch(void* const* d_in, const int* in_sizes, int n_in,
                              void* d_out, int out_size, void* d_ws, size_t ws_size,
                              hipStream_t stream) {
    const float* features = (const float*)d_in[0];
    const float* W1 = (const float*)d_in[1];
    const float* b1 = (const float*)d_in[2];
    const float* W2 = (const float*)d_in[3];
    const float* b2 = (const float*)d_in[4];
    const int* edge_index = (const int*)d_in[5];

    const int N = in_sizes[0] / F_IN;        // 100000
    const int E = in_sizes[5] / 2;           // 1600000
    const int Mpad = (N + 127) & ~127;       // 100096
    float* out = (float*)d_out;

    auto align256 = [](size_t x) { return (x + 255) & ~(size_t)255; };
    char* w = (char*)d_ws;
    int* cnt        = (int*)w;  w += align256((size_t)N * 4);
    int* rowStart   = (int*)w;  w += align256((size_t)(N + 1) * 4);
    int* rowPos     = (int*)w;  w += align256((size_t)N * 4);
    int* blockSums  = (int*)w;  w += align256(1024 * 4);
    int* flag64     = (int*)w;  w += 256;
    int* csrSrc     = (int*)w;  w += align256((size_t)E * 4);
    float* csrNorm  = (float*)w; w += align256((size_t)E * 4);
    float* dinv     = (float*)w; w += align256((size_t)N * 4);
    unsigned short* W1t = (unsigned short*)w; w += align256((size_t)HID * F_IN * 2);
    unsigned short* W2t = (unsigned short*)w; w += align256((size_t)NPAD * HID * 2);
    unsigned short* h1  = (unsigned short*)w; w += align256((size_t)Mpad * HID * 2);
    unsigned short* x1b = (unsigned short*)w; w += align256((size_t)Mpad * HID * 2);
    unsigned short* h2b = (unsigned short*)w; w += align256((size_t)Mpad * NPAD * 2);
    (void)ws_size;

    const int nB = (N + 1023) / 1024;
    const int eBlocks = (E + 255) / 256;
    const int nBlocks = (N + 255) / 256;
    const int waveBlocks = (N + 3) / 4;

    hipMemsetAsync(cnt, 0, (size_t)N * 4, stream);
    detect64_kernel<<<1, 256, 0, stream>>>(edge_index, flag64);
    count_kernel<<<eBlocks, 256, 0, stream>>>(edge_index, E, flag64, cnt);
    scan_block_sums<<<nB, 256, 0, stream>>>(cnt, blockSums, N);
    scan_sums_kernel<<<1, 64, 0, stream>>>(blockSums, nB, rowStart, N);
    dinv_kernel<<<nBlocks, 256, 0, stream>>>(cnt, dinv, N);
    scan_final<<<nB, 256, 0, stream>>>(cnt, blockSums, rowStart, rowPos, N);
    fill_kernel<<<eBlocks, 256, 0, stream>>>(edge_index, E, flag64, dinv, rowPos,
                                             csrSrc, csrNorm);

    convertW1t_kernel<<<(F_IN * HID) / 256, 256, 0, stream>>>(W1, W1t);
    convertW2t_kernel<<<(NPAD * HID + 255) / 256, 256, 0, stream>>>(W2, W2t);

    dim3 g1(Mpad / 128, HID / 128);
    gemm1_mfma_kernel<<<g1, 256, 0, stream>>>(features, W1t, h1, N);
    agg1_kernel<<<waveBlocks, 256, 0, stream>>>(h1, rowStart, csrSrc, csrNorm, dinv,
                                                b1, x1b, N);
    gemm2_mfma_kernel<<<Mpad / 128, 256, 0, stream>>>(x1b, W2t, h2b);
    agg2_kernel<<<waveBlocks, 256, 0, stream>>>(h2b, rowStart, csrSrc, csrNorm, dinv,
                                                b2, out, N);
}